// Round 7
// baseline (101.393 us; speedup 1.0000x reference)
//
#include <hip/hip_runtime.h>

typedef __attribute__((ext_vector_type(4))) _Float16 half4;
typedef __attribute__((ext_vector_type(8))) _Float16 half8;
typedef __attribute__((ext_vector_type(4))) float f32x4;

#define T_STEPS 24
#define N_NODES 325
#define RS_T 20800       // N*H elements per t
#define B_STRIDE 499200  // T*N*H elements per b
#define HLAST_OFF 31948800

__device__ __forceinline__ float fsigmoid(float x) {
    return __builtin_amdgcn_rcpf(1.0f + __expf(-x));
}
__device__ __forceinline__ float ftanh_f(float x) {
    return 1.0f - 2.0f * __builtin_amdgcn_rcpf(1.0f + __expf(2.0f * x));
}
__device__ __forceinline__ half4 cvt4(f32x4 a) {
    half4 r;
    r[0] = (_Float16)a[0]; r[1] = (_Float16)a[1];
    r[2] = (_Float16)a[2]; r[3] = (_Float16)a[3];
    return r;
}
__device__ __forceinline__ half8 cvt8(f32x4 a, f32x4 b) {
    half8 r;
    r[0]=(_Float16)a[0]; r[1]=(_Float16)a[1]; r[2]=(_Float16)a[2]; r[3]=(_Float16)a[3];
    r[4]=(_Float16)b[0]; r[5]=(_Float16)b[1]; r[6]=(_Float16)b[2]; r[7]=(_Float16)b[3];
    return r;
}

// 4-wave block, 32 batch rows (2 A-tiles/wave), wave wv owns gate cols
// {c0, 64+c0, 128+c0}, c0=16wv. Weights staged once to LDS (f16, XOR swizzle,
// conflict-free b128); weight frags hoisted into registers (cap 256 allows it).
// Both A-tiles share the same weight B-frags -> W per wave doubles, serial
// chain per step unchanged. lgkm-only barrier keeps global traffic in flight.
__global__ __launch_bounds__(256, 2) void gru_lds32_kernel(
    const float* __restrict__ data,   // [B,T,N,F]
    const float* __restrict__ h0,     // [B,N,H]
    const float* __restrict__ w_ih,   // [192,64]
    const float* __restrict__ w_hh,   // [192,64]
    const float* __restrict__ b_ih,   // [192]
    const float* __restrict__ b_hh,   // [192]
    float* __restrict__ out)          // [B,T,N,H] ++ [B,N,H]
{
    const int tid  = threadIdx.x;
    const int lane = tid & 63;
    const int wv   = tid >> 6;        // 0..3
    const int cl   = lane & 15;
    const int kg   = lane >> 4;
    const int c0   = wv * 16;
    const int row0 = blockIdx.x * 32;

    __shared__ __align__(16) char wlds[2][192 * 128]; // [ih,hh] f16 swizzled
    __shared__ __align__(16) char hlds[2][32 * 128];  // dbuf h, f16 swizzled

    // ---- stage weights to LDS (f16, swizzled) ----
#pragma unroll
    for (int mat = 0; mat < 2; ++mat) {
        const float* src = (mat == 0) ? w_ih : w_hh;
#pragma unroll
        for (int it = 0; it < 6; ++it) {
            const int c = it * 256 + tid;         // 0..1535
            const int n = c >> 3, j = c & 7;
            const f32x4 lo = *(const f32x4*)(src + n * 64 + j * 8);
            const f32x4 hi = *(const f32x4*)(src + n * 64 + j * 8 + 4);
            const int off = n * 128 + ((j * 16) ^ ((n & 7) << 4));
            *(half8*)(&wlds[mat][0] + off) = cvt8(lo, hi);
        }
    }
    // ---- stage h0 tile (32 rows x 64 cols) into hlds[0] ----
#pragma unroll
    for (int it = 0; it < 2; ++it) {
        const int c = it * 256 + tid;             // 0..511
        const int mrow = c >> 4, c4 = (c & 15) * 4;
        const f32x4 v = *(const f32x4*)(h0 + (row0 + mrow) * 64 + c4);
        const int off = mrow * 128 + ((c4 * 2) ^ ((mrow & 7) << 4));
        *(half4*)(&hlds[0][0] + off) = cvt4(v);
    }
    __syncthreads();

    // ---- weight B-frags: hoisted, held in registers across the t-loop ----
    const int wsw  = ((c0 + cl) & 7) << 4;
    const int wof0 = (c0 + cl) * 128 + ((     kg * 16) ^ wsw);
    const int wof1 = (c0 + cl) * 128 + ((64 + kg * 16) ^ wsw);
    const half8 wr0 = *(const half8*)(&wlds[0][0] + wof0);
    const half8 wr1 = *(const half8*)(&wlds[0][0] + wof1);
    const half8 wz0 = *(const half8*)(&wlds[0][0] + wof0 + 8192);
    const half8 wz1 = *(const half8*)(&wlds[0][0] + wof1 + 8192);
    const half8 wn0 = *(const half8*)(&wlds[0][0] + wof0 + 16384);
    const half8 wn1 = *(const half8*)(&wlds[0][0] + wof1 + 16384);
    const half8 ur0 = *(const half8*)(&wlds[1][0] + wof0);
    const half8 ur1 = *(const half8*)(&wlds[1][0] + wof1);
    const half8 uz0 = *(const half8*)(&wlds[1][0] + wof0 + 8192);
    const half8 uz1 = *(const half8*)(&wlds[1][0] + wof1 + 8192);
    const half8 un0 = *(const half8*)(&wlds[1][0] + wof0 + 16384);
    const half8 un1 = *(const half8*)(&wlds[1][0] + wof1 + 16384);

    // ---- bias splats as MFMA C-init ----
    const float bc0 = b_ih[      c0 + cl] + b_hh[      c0 + cl];
    const float bc1 = b_ih[ 64 + c0 + cl] + b_hh[ 64 + c0 + cl];
    const float bi2 = b_ih[128 + c0 + cl];
    const float bh2 = b_hh[128 + c0 + cl];
    const f32x4 bR4  = {bc0, bc0, bc0, bc0};
    const f32x4 bZ4  = {bc1, bc1, bc1, bc1};
    const f32x4 bNX4 = {bi2, bi2, bi2, bi2};
    const f32x4 bNH4 = {bh2, bh2, bh2, bh2};

    // ---- h A-frag LDS offsets (rows cl and cl+16; same swizzle since +16 keeps &7) ----
    const int hsw = (cl & 7) << 4;
    const int hr00 = cl * 128        + ((     kg * 16) ^ hsw);
    const int hr01 = cl * 128        + ((64 + kg * 16) ^ hsw);
    const int hr10 = (cl + 16) * 128 + ((     kg * 16) ^ hsw);
    const int hr11 = (cl + 16) * 128 + ((64 + kg * 16) ^ hsw);

    // ---- per-lane h master copies & addressing, 2 tiles ----
    float hreg[2][4];
    int obase[2][4];
#pragma unroll
    for (int tt = 0; tt < 2; ++tt)
#pragma unroll
        for (int r = 0; r < 4; ++r) {
            const int row = row0 + tt * 16 + kg * 4 + r;
            hreg[tt][r] = h0[row * 64 + c0 + cl];
            const int b = row / N_NODES, n = row % N_NODES;
            obase[tt][r] = b * B_STRIDE + n * 64 + c0 + cl;
        }
    int xbase[2];
#pragma unroll
    for (int tt = 0; tt < 2; ++tt) {
        const int xrow = row0 + tt * 16 + cl;
        xbase[tt] = (xrow / N_NODES) * B_STRIDE + (xrow % N_NODES) * 64;
    }

    // ---- x: t=0 current + t=1 prefetch in flight ----
    half8 xcur[2][2];
    f32x4 xpf[2][4];
#pragma unroll
    for (int tt = 0; tt < 2; ++tt) {
        f32x4 t0[4];
#pragma unroll
        for (int q = 0; q < 4; ++q)
            t0[q] = *(const f32x4*)(data + xbase[tt] + (q >> 1) * 32 + kg * 8 + (q & 1) * 4);
        xcur[tt][0] = cvt8(t0[0], t0[1]);
        xcur[tt][1] = cvt8(t0[2], t0[3]);
#pragma unroll
        for (int q = 0; q < 4; ++q)
            xpf[tt][q] = *(const f32x4*)(data + xbase[tt] + RS_T + (q >> 1) * 32 + kg * 8 + (q & 1) * 4);
    }

#pragma unroll 1
    for (int t = 0; t < T_STEPS; ++t) {
        const int cb = t & 1;

        // h A-frags (the only post-barrier LDS dependency)
        const half8 hA00 = *(const half8*)(&hlds[cb][0] + hr00);
        const half8 hA01 = *(const half8*)(&hlds[cb][0] + hr01);
        const half8 hA10 = *(const half8*)(&hlds[cb][0] + hr10);
        const half8 hA11 = *(const half8*)(&hlds[cb][0] + hr11);

        // next x arrives; issue t+2 prefetch
        half8 xnext[2][2];
        const int tl = (t + 2 < T_STEPS) ? t + 2 : T_STEPS - 1;
#pragma unroll
        for (int tt = 0; tt < 2; ++tt) {
            xnext[tt][0] = cvt8(xpf[tt][0], xpf[tt][1]);
            xnext[tt][1] = cvt8(xpf[tt][2], xpf[tt][3]);
#pragma unroll
            for (int q = 0; q < 4; ++q)
                xpf[tt][q] = *(const f32x4*)(data + xbase[tt] + tl * RS_T +
                                             (q >> 1) * 32 + kg * 8 + (q & 1) * 4);
        }

        // ---- 24 MFMAs: 2 tiles sharing the same weight B-frags ----
        f32x4 aR[2], aZ[2], aNX[2], aNH[2];
#pragma unroll
        for (int tt = 0; tt < 2; ++tt) {
            const half8 h0f = tt ? hA10 : hA00;
            const half8 h1f = tt ? hA11 : hA01;
            aR[tt]  = __builtin_amdgcn_mfma_f32_16x16x32_f16(xcur[tt][0], wr0, bR4,  0, 0, 0);
            aZ[tt]  = __builtin_amdgcn_mfma_f32_16x16x32_f16(xcur[tt][0], wz0, bZ4,  0, 0, 0);
            aNX[tt] = __builtin_amdgcn_mfma_f32_16x16x32_f16(xcur[tt][0], wn0, bNX4, 0, 0, 0);
            aNH[tt] = __builtin_amdgcn_mfma_f32_16x16x32_f16(h0f,         un0, bNH4, 0, 0, 0);
            aR[tt]  = __builtin_amdgcn_mfma_f32_16x16x32_f16(xcur[tt][1], wr1, aR[tt],  0, 0, 0);
            aZ[tt]  = __builtin_amdgcn_mfma_f32_16x16x32_f16(xcur[tt][1], wz1, aZ[tt],  0, 0, 0);
            aNX[tt] = __builtin_amdgcn_mfma_f32_16x16x32_f16(xcur[tt][1], wn1, aNX[tt], 0, 0, 0);
            aNH[tt] = __builtin_amdgcn_mfma_f32_16x16x32_f16(h1f,         un1, aNH[tt], 0, 0, 0);
            aR[tt]  = __builtin_amdgcn_mfma_f32_16x16x32_f16(h0f,         ur0, aR[tt],  0, 0, 0);
            aZ[tt]  = __builtin_amdgcn_mfma_f32_16x16x32_f16(h0f,         uz0, aZ[tt],  0, 0, 0);
            aR[tt]  = __builtin_amdgcn_mfma_f32_16x16x32_f16(h1f,         ur1, aR[tt],  0, 0, 0);
            aZ[tt]  = __builtin_amdgcn_mfma_f32_16x16x32_f16(h1f,         uz1, aZ[tt],  0, 0, 0);
        }

        // ---- gates + update + store + publish ----
#pragma unroll
        for (int tt = 0; tt < 2; ++tt) {
#pragma unroll
            for (int r = 0; r < 4; ++r) {
                const float rg = fsigmoid(aR[tt][r]);
                const float zg = fsigmoid(aZ[tt][r]);
                const float cd = ftanh_f(aNX[tt][r] + rg * aNH[tt][r]);
                const float hn = cd + zg * (hreg[tt][r] - cd);
                hreg[tt][r] = hn;
                out[t * RS_T + obase[tt][r]] = hn;
            }
        }

        if (t + 1 < T_STEPS) {
            const int nb = (t + 1) & 1;
#pragma unroll
            for (int tt = 0; tt < 2; ++tt)
#pragma unroll
                for (int r = 0; r < 4; ++r) {
                    const int mrow = tt * 16 + kg * 4 + r;
                    const int off = mrow * 128 + (((c0 + cl) * 2) ^ ((mrow & 7) << 4));
                    *(_Float16*)(&hlds[nb][0] + off) = (_Float16)hreg[tt][r];
                }
            asm volatile("s_waitcnt lgkmcnt(0)" ::: "memory");
            __builtin_amdgcn_s_barrier();
            __builtin_amdgcn_sched_barrier(0);
        }
#pragma unroll
        for (int tt = 0; tt < 2; ++tt) {
            xcur[tt][0] = xnext[tt][0];
            xcur[tt][1] = xnext[tt][1];
        }
    }

    // h_last
#pragma unroll
    for (int tt = 0; tt < 2; ++tt)
#pragma unroll
        for (int r = 0; r < 4; ++r) {
            const int row = row0 + tt * 16 + kg * 4 + r;
            out[HLAST_OFF + row * 64 + c0 + cl] = hreg[tt][r];
        }
}

extern "C" void kernel_launch(void* const* d_in, const int* in_sizes, int n_in,
                              void* d_out, int out_size, void* d_ws, size_t ws_size,
                              hipStream_t stream) {
    const float* data = (const float*)d_in[1];
    const float* h0   = (const float*)d_in[2];
    const float* w_ih = (const float*)d_in[3];
    const float* w_hh = (const float*)d_in[4];
    const float* b_ih = (const float*)d_in[5];
    const float* b_hh = (const float*)d_in[6];
    float* out = (float*)d_out;

    // 20800 rows / 32 per block = 650 blocks, 4 waves each
    gru_lds32_kernel<<<dim3(650), dim3(256), 0, stream>>>(
        data, h0, w_ih, w_hh, b_ih, b_hh, out);
}

// Round 8
// 92.012 us; speedup vs baseline: 1.1020x; 1.1020x over previous
//
#include <hip/hip_runtime.h>

typedef __attribute__((ext_vector_type(4))) _Float16 half4;
typedef __attribute__((ext_vector_type(8))) _Float16 half8;
typedef __attribute__((ext_vector_type(4))) float f32x4;

#define T_STEPS 24
#define N_NODES 325
#define RS_T 20800       // N*H elements per t
#define B_STRIDE 499200  // T*N*H elements per b
#define HLAST_OFF 31948800

__device__ __forceinline__ float fsigmoid(float x) {
    return __builtin_amdgcn_rcpf(1.0f + __expf(-x));
}
__device__ __forceinline__ float ftanh_f(float x) {
    return 1.0f - 2.0f * __builtin_amdgcn_rcpf(1.0f + __expf(2.0f * x));
}
__device__ __forceinline__ half4 cvt4(f32x4 a) {
    half4 r;
    r[0] = (_Float16)a[0]; r[1] = (_Float16)a[1];
    r[2] = (_Float16)a[2]; r[3] = (_Float16)a[3];
    return r;
}
__device__ __forceinline__ half8 cvt8(f32x4 a, f32x4 b) {
    half8 r;
    r[0]=(_Float16)a[0]; r[1]=(_Float16)a[1]; r[2]=(_Float16)a[2]; r[3]=(_Float16)a[3];
    r[4]=(_Float16)b[0]; r[5]=(_Float16)b[1]; r[6]=(_Float16)b[2]; r[7]=(_Float16)b[3];
    return r;
}
// Compiler-invisible load: no auto s_waitcnt is generated for it.
// volatile asms keep program order among themselves; dst dep orders consumers.
__device__ __forceinline__ void gload4(f32x4& dst, const float* p) {
    asm volatile("global_load_dwordx4 %0, %1, off" : "=v"(dst) : "v"(p) : "memory");
}

// R6 structure + hand-counted vmcnt pipeline for x.
// 4-wave block, 16 batch rows; wave wv owns gate cols {c0,64+c0,128+c0}.
// Weights in LDS (f16, XOR swizzle, conflict-free b128). h exchanged via
// swizzled LDS with lgkm-only barrier. x loads via inline-asm 3-slot rotation;
// exactly one s_waitcnt vmcnt(12) per step (L(t+2),L(t+3),S(t) in flight).
__global__ __launch_bounds__(256, 3) void gru_async_kernel(
    const float* __restrict__ data,   // [B,T,N,F]
    const float* __restrict__ h0,     // [B,N,H]
    const float* __restrict__ w_ih,   // [192,64]
    const float* __restrict__ w_hh,   // [192,64]
    const float* __restrict__ b_ih,   // [192]
    const float* __restrict__ b_hh,   // [192]
    float* __restrict__ out)          // [B,T,N,H] ++ [B,N,H]
{
    const int tid  = threadIdx.x;
    const int lane = tid & 63;
    const int wv   = tid >> 6;        // 0..3
    const int cl   = lane & 15;
    const int kg   = lane >> 4;
    const int c0   = wv * 16;
    const int row0 = blockIdx.x * 16;

    __shared__ __align__(16) char wlds[2][192 * 128]; // [ih,hh] f16 swizzled
    __shared__ __align__(16) char hlds[2][16 * 128];  // dbuf h, f16 swizzled

    // ---- x addressing + earliest possible issue of L(0) ----
    const int xrow = row0 + cl;
    const int xb = xrow / N_NODES, xn = xrow % N_NODES;
    const int xbase = xb * B_STRIDE + xn * 64;

    f32x4 xfA[4], xfB[4], xfC[4];
#define XLOAD(SL, TL)                                                          \
    do {                                                                       \
        const float* _pb = data + xbase + (TL) * RS_T + kg * 8;                \
        gload4(SL[0], _pb);                                                    \
        gload4(SL[1], _pb + 4);                                                \
        gload4(SL[2], _pb + 32);                                               \
        gload4(SL[3], _pb + 36);                                               \
    } while (0)

    XLOAD(xfA, 0);   // L(0) rides under the staging phase

    // ---- stage weights to LDS (f16, swizzled) ----
#pragma unroll
    for (int mat = 0; mat < 2; ++mat) {
        const float* src = (mat == 0) ? w_ih : w_hh;
#pragma unroll
        for (int it = 0; it < 6; ++it) {
            const int c = it * 256 + tid;         // 0..1535
            const int n = c >> 3, j = c & 7;
            const f32x4 lo = *(const f32x4*)(src + n * 64 + j * 8);
            const f32x4 hi = *(const f32x4*)(src + n * 64 + j * 8 + 4);
            const int off = n * 128 + ((j * 16) ^ ((n & 7) << 4));
            *(half8*)(&wlds[mat][0] + off) = cvt8(lo, hi);
        }
    }
    // ---- stage h0 tile into hlds[0] (f16, swizzled) ----
    {
        const int m = tid >> 4, c4 = (tid & 15) * 4;
        const f32x4 v = *(const f32x4*)(h0 + (row0 + m) * 64 + c4);
        const int off = m * 128 + ((c4 * 2) ^ ((m & 7) << 4));
        *(half4*)(&hlds[0][0] + off) = cvt4(v);
    }
    __syncthreads();

    // ---- loop-invariant LDS byte offsets ----
    const int wsw  = ((c0 + cl) & 7) << 4;
    const int wof0 = (c0 + cl) * 128 + ((     kg * 16) ^ wsw);
    const int wof1 = (c0 + cl) * 128 + ((64 + kg * 16) ^ wsw);
    const int hsw  = (cl & 7) << 4;
    const int hr0  = cl * 128 + ((     kg * 16) ^ hsw);
    const int hr1  = cl * 128 + ((64 + kg * 16) ^ hsw);

    // ---- bias splats as MFMA C-init ----
    const float bc0 = b_ih[      c0 + cl] + b_hh[      c0 + cl];
    const float bc1 = b_ih[ 64 + c0 + cl] + b_hh[ 64 + c0 + cl];
    const float bi2 = b_ih[128 + c0 + cl];
    const float bh2 = b_hh[128 + c0 + cl];
    const f32x4 bR4  = {bc0, bc0, bc0, bc0};
    const f32x4 bZ4  = {bc1, bc1, bc1, bc1};
    const f32x4 bNX4 = {bi2, bi2, bi2, bi2};
    const f32x4 bNH4 = {bh2, bh2, bh2, bh2};

    // ---- per-lane h master copy + addressing ----
    const int hb0 = (row0 + kg * 4) * 64 + c0 + cl;
    float hreg[4];
#pragma unroll
    for (int r = 0; r < 4; ++r) hreg[r] = h0[hb0 + 64 * r];
    int obase[4];
#pragma unroll
    for (int r = 0; r < 4; ++r) {
        const int row = row0 + kg * 4 + r;
        const int b = row / N_NODES, n = row % N_NODES;
        obase[r] = b * B_STRIDE + n * 64 + c0 + cl;
    }

    // ---- prologue: consume L(0), fill pipeline with L(1), L(2) ----
    half8 xcur[2];
    asm volatile("s_waitcnt vmcnt(0)"
                 : "+v"(xfA[0]), "+v"(xfA[1]), "+v"(xfA[2]), "+v"(xfA[3])
                 :: "memory");
    xcur[0] = cvt8(xfA[0], xfA[1]);
    xcur[1] = cvt8(xfA[2], xfA[3]);
    XLOAD(xfB, 1);
    XLOAD(xfC, 2);

    // One GRU step. XI: slot to refill with L(t+3); XC: slot holding L(t+1).
#define STEP(T, XI, XC)                                                        \
    do {                                                                       \
        const int t = (T);                                                     \
        const int tl = (t + 3 < T_STEPS) ? t + 3 : T_STEPS - 1;                \
        XLOAD(XI, tl);                                                         \
        const int cb = t & 1;                                                  \
        const half8 hA0 = *(const half8*)(&hlds[cb][0] + hr0);                 \
        const half8 hA1 = *(const half8*)(&hlds[cb][0] + hr1);                 \
        const half8 wr0 = *(const half8*)(&wlds[0][0] + wof0);                 \
        const half8 wr1 = *(const half8*)(&wlds[0][0] + wof1);                 \
        const half8 wz0 = *(const half8*)(&wlds[0][0] + wof0 + 8192);          \
        const half8 wz1 = *(const half8*)(&wlds[0][0] + wof1 + 8192);          \
        const half8 wn0 = *(const half8*)(&wlds[0][0] + wof0 + 16384);         \
        const half8 wn1 = *(const half8*)(&wlds[0][0] + wof1 + 16384);         \
        const half8 ur0 = *(const half8*)(&wlds[1][0] + wof0);                 \
        const half8 ur1 = *(const half8*)(&wlds[1][0] + wof1);                 \
        const half8 uz0 = *(const half8*)(&wlds[1][0] + wof0 + 8192);          \
        const half8 uz1 = *(const half8*)(&wlds[1][0] + wof1 + 8192);          \
        const half8 un0 = *(const half8*)(&wlds[1][0] + wof0 + 16384);         \
        const half8 un1 = *(const half8*)(&wlds[1][0] + wof1 + 16384);         \
        f32x4 aR  = __builtin_amdgcn_mfma_f32_16x16x32_f16(xcur[0], wr0, bR4,  0, 0, 0); \
        f32x4 aZ  = __builtin_amdgcn_mfma_f32_16x16x32_f16(xcur[0], wz0, bZ4,  0, 0, 0); \
        f32x4 aNX = __builtin_amdgcn_mfma_f32_16x16x32_f16(xcur[0], wn0, bNX4, 0, 0, 0); \
        f32x4 aNH = __builtin_amdgcn_mfma_f32_16x16x32_f16(hA0,     un0, bNH4, 0, 0, 0); \
        aR  = __builtin_amdgcn_mfma_f32_16x16x32_f16(xcur[1], wr1, aR,  0, 0, 0); \
        aZ  = __builtin_amdgcn_mfma_f32_16x16x32_f16(xcur[1], wz1, aZ,  0, 0, 0); \
        aNX = __builtin_amdgcn_mfma_f32_16x16x32_f16(xcur[1], wn1, aNX, 0, 0, 0); \
        aNH = __builtin_amdgcn_mfma_f32_16x16x32_f16(hA1,     un1, aNH, 0, 0, 0); \
        aR  = __builtin_amdgcn_mfma_f32_16x16x32_f16(hA0,     ur0, aR,  0, 0, 0); \
        aZ  = __builtin_amdgcn_mfma_f32_16x16x32_f16(hA0,     uz0, aZ,  0, 0, 0); \
        aR  = __builtin_amdgcn_mfma_f32_16x16x32_f16(hA1,     ur1, aR,  0, 0, 0); \
        aZ  = __builtin_amdgcn_mfma_f32_16x16x32_f16(hA1,     uz1, aZ,  0, 0, 0); \
        float hn[4];                                                           \
        _Pragma("unroll")                                                      \
        for (int r = 0; r < 4; ++r) {                                          \
            const float rg = fsigmoid(aR[r]);                                  \
            const float zg = fsigmoid(aZ[r]);                                  \
            const float cd = ftanh_f(aNX[r] + rg * aNH[r]);                    \
            hn[r] = cd + zg * (hreg[r] - cd);                                  \
            hreg[r] = hn[r];                                                   \
            out[t * RS_T + obase[r]] = hn[r];                                  \
        }                                                                      \
        asm volatile("s_waitcnt vmcnt(12)"                                     \
                     : "+v"(XC[0]), "+v"(XC[1]), "+v"(XC[2]), "+v"(XC[3])      \
                     :: "memory");                                             \
        xcur[0] = cvt8(XC[0], XC[1]);                                          \
        xcur[1] = cvt8(XC[2], XC[3]);                                          \
        if (t + 1 < T_STEPS) {                                                 \
            const int nb = (t + 1) & 1;                                        \
            _Pragma("unroll")                                                  \
            for (int r = 0; r < 4; ++r) {                                      \
                const int mrow = kg * 4 + r;                                   \
                const int off = mrow * 128 + (((c0 + cl) * 2) ^ ((mrow & 7) << 4)); \
                *(_Float16*)(&hlds[nb][0] + off) = (_Float16)hn[r];            \
            }                                                                  \
            asm volatile("s_waitcnt lgkmcnt(0)" ::: "memory");                 \
            __builtin_amdgcn_s_barrier();                                      \
            __builtin_amdgcn_sched_barrier(0);                                 \
        }                                                                      \
    } while (0)

#pragma unroll 1
    for (int tb = 0; tb < T_STEPS; tb += 3) {
        STEP(tb,     xfA, xfB);
        STEP(tb + 1, xfB, xfC);
        STEP(tb + 2, xfC, xfA);
    }

    // h_last
#pragma unroll
    for (int r = 0; r < 4; ++r)
        out[HLAST_OFF + hb0 + 64 * r] = hreg[r];
#undef STEP
#undef XLOAD
}

extern "C" void kernel_launch(void* const* d_in, const int* in_sizes, int n_in,
                              void* d_out, int out_size, void* d_ws, size_t ws_size,
                              hipStream_t stream) {
    const float* data = (const float*)d_in[1];
    const float* h0   = (const float*)d_in[2];
    const float* w_ih = (const float*)d_in[3];
    const float* w_hh = (const float*)d_in[4];
    const float* b_ih = (const float*)d_in[5];
    const float* b_hh = (const float*)d_in[6];
    float* out = (float*)d_out;

    // 20800 rows / 16 per block = 1300 blocks, 4 waves each
    gru_async_kernel<<<dim3(1300), dim3(256), 0, stream>>>(
        data, h0, w_ih, w_hh, b_ih, b_hh, out);
}